// Round 9
// baseline (324.178 us; speedup 1.0000x reference)
//
#include <hip/hip_runtime.h>
#include <cstdint>
#include <cstddef>

#define NBg 64    // num gt slots
#define NCg 80    // num classes
#define KTOP 10
#define K16 16    // padded list size for bitonic merging

typedef unsigned long long u64k;

// CIoU exactly mirroring the reference op order, f32, no FMA contraction.
__device__ __forceinline__ float ciou_dev(float gx1, float gy1, float gx2, float gy2,
                                          float px1, float py1, float px2, float py2) {
#pragma clang fp contract(off)
  const float keps = 1e-7f;
  float w1 = gx2 - gx1;
  float h1 = (gy2 - gy1) + keps;
  float w2 = px2 - px1;
  float h2 = (py2 - py1) + keps;
  float iw = fminf(gx2, px2) - fmaxf(gx1, px1);
  float ih = fminf(gy2, py2) - fmaxf(gy1, py1);
  float inter = fmaxf(iw, 0.0f) * fmaxf(ih, 0.0f);
  float uni = w1 * h1 + w2 * h2 - inter + keps;
  float iou = inter / uni;
  float cw = fmaxf(gx2, px2) - fminf(gx1, px1);
  float ch = fmaxf(gy2, py2) - fminf(gy1, py1);
  float c2 = cw * cw + ch * ch + keps;
  float dx = (gx1 + gx2) * 0.5f - (px1 + px2) * 0.5f;
  float dy = (gy1 + gy2) * 0.5f - (py1 + py2) * 0.5f;
  float rho2 = dx * dx + dy * dy;
  float q2 = w2 / h2;
  float q1 = w1 / h1;
  float t = (float)atan((double)q2) - (float)atan((double)q1);
  float v = 0.4052847345693511f * (t * t);
  float alpha = v / ((v - iou) + 1.0000001f);
  return iou - (rho2 / c2 + v * alpha);
}

// am = sqrt(score) * overlap^6 with the exact double-rounded forms used since r1.
__device__ __forceinline__ float am_dev(float sc, float ov) {
  float f1 = (float)sqrt((double)sc);
  double o = (double)ov;
  double o3 = o * o * o;
  return f1 * (float)(o3 * o3);
}

// key = (float_bits(am) << 32) | ~idx : total order == (am desc, idx asc).
__device__ __forceinline__ u64k mk_key(float am, int a) {
  return ((u64k)__float_as_uint(am) << 32) | (unsigned)(~a);
}

// Merge two sorted-desc 16-lists (unique keys), keep top-16 sorted desc in L.
__device__ __forceinline__ void merge16(u64k (&L)[K16], const u64k (&B)[K16]) {
  u64k C[K16];
#pragma unroll
  for (int i = 0; i < K16; i++) {
    u64k x = L[i], y = B[15 - i];
    C[i] = x > y ? x : y;
  }
#pragma unroll
  for (int s = 8; s > 0; s >>= 1) {
#pragma unroll
    for (int i = 0; i < K16; i++) {
      if ((i & s) == 0) {
        u64k x = C[i], y = C[i | s];
        C[i] = x > y ? x : y;
        C[i | s] = x > y ? y : x;
      }
    }
  }
#pragma unroll
  for (int i = 0; i < K16; i++) L[i] = C[i];
}

// Device-scope grid barrier (sense-reversing). All blocks co-resident
// (grid=512, __launch_bounds__(256,2) -> 2 blocks/CU x 256 CUs).
__device__ __forceinline__ void grid_barrier(unsigned* cnt, unsigned* gen) {
  __syncthreads();
  if (threadIdx.x == 0) {
    __threadfence();
    unsigned g = __hip_atomic_load(gen, __ATOMIC_RELAXED, __HIP_MEMORY_SCOPE_AGENT);
    unsigned arrived =
        __hip_atomic_fetch_add(cnt, 1u, __ATOMIC_ACQ_REL, __HIP_MEMORY_SCOPE_AGENT) + 1;
    if (arrived == gridDim.x) {
      __hip_atomic_store(cnt, 0u, __ATOMIC_RELAXED, __HIP_MEMORY_SCOPE_AGENT);
      __hip_atomic_fetch_add(gen, 1u, __ATOMIC_RELEASE, __HIP_MEMORY_SCOPE_AGENT);
    } else {
      while (__hip_atomic_load(gen, __ATOMIC_ACQUIRE, __HIP_MEMORY_SCOPE_AGENT) == g) {
        __builtin_amdgcn_s_sleep(8);
      }
    }
    __threadfence();
  }
  __syncthreads();
}

// Fused: Phase A (topk per gt row, 2 rows/block, 128 threads each)
//        -> grid barrier ->
//        Phase B (per-anchor resolve, 1-2 tiles of 256 anchors per block)
//        -> grid barrier ->
//        Phase C (norm + one-hot scores from LDS stash).
__global__ __launch_bounds__(256, 2) void fused_all(
    const float* __restrict__ pd_scores,
    const float* __restrict__ pd_bboxes,
    const float* __restrict__ anc,
    const float* __restrict__ gt_labels,
    const float* __restrict__ gt_bboxes,
    const int* __restrict__ mask_gt,
    int* __restrict__ sel,
    float* __restrict__ posAlign,
    float* __restrict__ posOv,
    unsigned* __restrict__ bar,
    float* __restrict__ out_tb,
    float* __restrict__ out_ts,
    float* __restrict__ out_fg,
    int NA, int nTiles, int totalTiles) {
  int bid = blockIdx.x;
  int tid = threadIdx.x;
  int lane = tid & 63;
  int wave = tid >> 6;      // 0..3
  int half = tid >> 7;      // 0,1
  int htid = tid & 127;

  __shared__ u64k xl[4][K16];
  __shared__ float4 sg[NBg];
  __shared__ int svalid[NBg], slbl[NBg], sglpos[NBg];
  __shared__ unsigned mlo[256], mhi[256];
  __shared__ float s_amv[2][256];
  __shared__ int s_tgt[2][256];
  __shared__ float spa[NBg], spo[NBg];
  __shared__ int slbl2[NBg];
  __shared__ float snorm[256];
  __shared__ int slab[256];

  const float2* anc2 = (const float2*)anc;

  // ---------------- Phase A: top-10 per gt row ----------------
  int row = 2 * bid + half;          // 0..1023
  int rb = row >> 6;                 // batch of this row
  if (htid == 0) { posAlign[row] = 0.0f; posOv[row] = 0.0f; }
  bool rowvalid = mask_gt[row] != 0;

  const float* g = gt_bboxes + (size_t)row * 4;
  float gx1 = g[0], gy1 = g[1], gx2 = g[2], gy2 = g[3];

  u64k L[K16];
#pragma unroll
  for (int q = 0; q < K16; q++) L[q] = 0;

  if (rowvalid) {
    float gl = gt_labels[row];
    int lbl = gl > 0.0f ? (int)gl : 0;
    bool glpos = (gl >= 0.0f);

    auto rect = [&](float s, int n, int& x0, int& y0, int& w, int& h) {
      int i0 = (int)floorf(gx1 / s - 0.5f) - 1; if (i0 < 0) i0 = 0;
      int i1 = (int)ceilf (gx2 / s - 0.5f) + 1; if (i1 > n - 1) i1 = n - 1;
      int j0 = (int)floorf(gy1 / s - 0.5f) - 1; if (j0 < 0) j0 = 0;
      int j1 = (int)ceilf (gy2 / s - 0.5f) + 1; if (j1 > n - 1) j1 = n - 1;
      x0 = i0; y0 = j0;
      w = i1 - i0 + 1; h = j1 - j0 + 1;
      if (w < 0) w = 0;
      if (h < 0) h = 0;
    };
    int x00, y00, w0, h0, x01, y01, w1, h1, x02, y02, w2, h2;
    rect( 8.0f, 80, x00, y00, w0, h0);
    rect(16.0f, 40, x01, y01, w1, h1);
    rect(32.0f, 20, x02, y02, w2, h2);
    int sz0 = w0 * h0, sz1 = w1 * h1, sz2 = w2 * h2;
    int tot = sz0 + sz1 + sz2;

    u64k k[KTOP];
#pragma unroll
    for (int q = 0; q < KTOP; q++) k[q] = 0;

    auto ins = [&](u64k key) {
      if (key > k[KTOP - 1]) {
        k[KTOP - 1] = key;
#pragma unroll
        for (int q = KTOP - 1; q > 0; q--) {
          if (k[q] > k[q - 1]) { u64k t = k[q]; k[q] = k[q - 1]; k[q - 1] = t; }
        }
      }
    };

    for (int c = htid; c < tot; c += 128) {
      int cc, x0, y0, w, nbase, ngrid; float ss;
      if (c < sz0)            { cc = c;             x0 = x00; y0 = y00; w = w0; nbase = 0;    ngrid = 80; ss =  8.0f; }
      else if (c < sz0 + sz1) { cc = c - sz0;       x0 = x01; y0 = y01; w = w1; nbase = 6400; ngrid = 40; ss = 16.0f; }
      else                    { cc = c - sz0 - sz1; x0 = x02; y0 = y02; w = w2; nbase = 8000; ngrid = 20; ss = 32.0f; }
      int iy = y0 + cc / w;
      int ix = x0 + cc % w;
      float ax = ((float)ix + 0.5f) * ss;   // bit-identical to stored anc
      float ay = ((float)iy + 0.5f) * ss;
      float dmin = fminf(fminf(ax - gx1, ay - gy1), fminf(gx2 - ax, gy2 - ay));
      if (dmin > 1e-9f) {
        int a = nbase + iy * ngrid + ix;
        const float4 pb = ((const float4*)pd_bboxes)[(size_t)rb * NA + a];
        float ci = ciou_dev(gx1, gy1, gx2, gy2, pb.x, pb.y, pb.z, pb.w);
        float ov = ci > 0.0f ? ci : 0.0f;
        float sc = glpos ? pd_scores[((size_t)rb * NA + a) * NCg + lbl] : 0.0f;
        ins(mk_key(am_dev(sc, ov), a));
      }
    }
#pragma unroll
    for (int q = 0; q < KTOP; q++) L[q] = k[q];
  }

  // butterfly within wave (zeros harmless for invalid rows)
#pragma unroll
  for (int step = 0; step < 6; step++) {
    u64k B[K16];
#pragma unroll
    for (int q = 0; q < K16; q++)
      B[q] = __shfl_xor((unsigned long long)L[q], 1 << step, 64);
    merge16(L, B);
  }
  if (lane < K16) xl[wave][lane] = L[lane];
  __syncthreads();
  if ((wave & 1) == 0) {
    u64k B[K16];
#pragma unroll
    for (int q = 0; q < K16; q++) B[q] = xl[wave | 1][q];
    merge16(L, B);                  // row's global top-16, sorted desc
    if (lane == 0 && rowvalid) {
      int npos = 0;
#pragma unroll
      for (int q = 0; q < KTOP; q++) if ((L[q] >> 32) != 0) npos++;
      int cand = 0;
      for (int slot = 0; slot < KTOP; slot++) {
        int a;
        if (slot < npos) {
          a = (int)~(unsigned)L[slot];
        } else {
          bool moved = true;
          while (moved) {
            moved = false;
#pragma unroll
            for (int q = 0; q < KTOP; q++)
              if (q < npos && (int)~(unsigned)L[q] == cand) { cand++; moved = true; }
          }
          a = cand++;
        }
        float2 ap = anc2[a];
        float dmin = fminf(fminf(ap.x - gx1, ap.y - gy1),
                           fminf(gx2 - ap.x, gy2 - ap.y));
        sel[row * KTOP + slot] = (dmin > 1e-9f) ? a : -1;
      }
    }
  }
  if (!rowvalid && htid < KTOP) sel[row * KTOP + htid] = -1;

  grid_barrier(&bar[0], &bar[1]);

  // ---------------- Phase B: per-anchor resolve (1-2 tiles) ----------------
  int extra = totalTiles - gridDim.x;   // 16
  for (int ti = 0; ti < 2; ti++) {
    int t = (ti == 0) ? bid : (bid < extra ? (int)gridDim.x + bid : -1);
    __syncthreads();   // protect LDS reuse
    int b = 0, a0 = 0, a = 0;
    if (t >= 0) {
      b = t / nTiles;
      a0 = (t % nTiles) * 256;
      a = a0 + tid;
      mlo[tid] = 0u; mhi[tid] = 0u;
      if (tid < NBg) {
        int j = tid;
        const float* gg = gt_bboxes + ((size_t)b * NBg + j) * 4;
        sg[j] = make_float4(gg[0], gg[1], gg[2], gg[3]);
        svalid[j] = mask_gt[b * NBg + j];
        float gl = gt_labels[b * NBg + j];
        slbl[j] = gl > 0.0f ? (int)gl : 0;
        sglpos[j] = (gl >= 0.0f) ? 1 : 0;
      }
    }
    __syncthreads();
    if (t >= 0) {
      for (int i = tid; i < NBg * KTOP; i += 256) {
        int e = sel[b * NBg * KTOP + i];
        int d = e - a0;
        if (d >= 0 && d < 256) {
          int j = i / KTOP;
          unsigned bit = 1u << (j & 31);
          if (j < 32) atomicOr(&mlo[d], bit); else atomicOr(&mhi[d], bit);
        }
      }
    }
    __syncthreads();
    if (t >= 0 && a < NA) {
      unsigned lo = mlo[tid], hi = mhi[tid];
      int cnt = __popc(lo) + __popc(hi);
      int first = lo ? (__ffs(lo) - 1) : (hi ? 32 + __ffs(hi) - 1 : 0);

      float ax = anc[2 * a], ay = anc[2 * a + 1];
      float px1 = 0.f, py1 = 0.f, px2 = 0.f, py2 = 0.f;
      if (cnt > 0) {
        const float* pb = pd_bboxes + ((size_t)b * NA + a) * 4;
        px1 = pb[0]; py1 = pb[1]; px2 = pb[2]; py2 = pb[3];
      }
      int tt = 0;
      float fg = 0.0f;
      float ovt = -1.0f;
      if (cnt == 1) {
        tt = first; fg = 1.0f;
      } else if (cnt > 1) {
        unsigned bm_lo = 0u, bm_hi = 0u;
        for (int jj = 0; jj < NBg; jj++) {
          if (svalid[jj]) {
            float4 gq = sg[jj];
            float dmin = fminf(fminf(ax - gq.x, ay - gq.y), fminf(gq.z - ax, gq.w - ay));
            if (dmin > 1e-9f) {
              if (jj < 32) bm_lo |= 1u << jj; else bm_hi |= 1u << (jj - 32);
            }
          }
        }
        float best = 0.0f;
        tt = 0;
        unsigned m = bm_lo; int base = 0;
        for (int hh = 0; hh < 2; hh++) {
          while (m) {
            int jj = base + __ffs(m) - 1; m &= m - 1;
            float4 gq = sg[jj];
            float ci = ciou_dev(gq.x, gq.y, gq.z, gq.w, px1, py1, px2, py2);
            float ov = ci > 0.0f ? ci : 0.0f;
            if (ov > best) { best = ov; tt = jj; }
          }
          m = bm_hi; base = 32;
        }
        fg = 1.0f;
        ovt = best;
      }
      out_fg[(size_t)b * NA + a] = fg;
      float4 gb = sg[tt];
      ((float4*)out_tb)[(size_t)b * NA + a] = gb;
      float amval = 0.0f;
      if (fg > 0.0f) {
        float ov;
        if (ovt >= 0.0f) {
          ov = ovt;
        } else {
          float ci = ciou_dev(gb.x, gb.y, gb.z, gb.w, px1, py1, px2, py2);
          ov = ci > 0.0f ? ci : 0.0f;
        }
        float sc = sglpos[tt] ? pd_scores[((size_t)b * NA + a) * NCg + slbl[tt]] : 0.0f;
        amval = am_dev(sc, ov);
        atomicMax((int*)(posAlign + b * NBg + tt), __float_as_int(amval));
        atomicMax((int*)(posOv + b * NBg + tt), __float_as_int(ov));
      }
      s_tgt[ti][tid] = (fg > 0.0f) ? tt : -1;
      s_amv[ti][tid] = amval;
    }
  }

  grid_barrier(&bar[0], &bar[1]);

  // ---------------- Phase C: norm + one-hot scores ----------------
  for (int ti = 0; ti < 2; ti++) {
    int t = (ti == 0) ? bid : (bid < extra ? (int)gridDim.x + bid : -1);
    __syncthreads();
    int b = 0, a0 = 0;
    if (t >= 0) {
      b = t / nTiles;
      a0 = (t % nTiles) * 256;
      if (tid < NBg) {
        int idx = b * NBg + tid;
        spa[tid] = __int_as_float(
            __hip_atomic_load((int*)&posAlign[idx], __ATOMIC_RELAXED, __HIP_MEMORY_SCOPE_AGENT));
        spo[tid] = __int_as_float(
            __hip_atomic_load((int*)&posOv[idx], __ATOMIC_RELAXED, __HIP_MEMORY_SCOPE_AGENT));
        float gl = gt_labels[idx];
        slbl2[tid] = gl > 0.0f ? (int)gl : 0;
      }
    }
    __syncthreads();
    if (t >= 0) {
      int tt = s_tgt[ti][tid];
      float norm = 0.0f;
      int lbl = -1;
      if (tt >= 0) {
        norm = s_amv[ti][tid] * spo[tt] / (spa[tt] + 1e-9f);
        lbl = slbl2[tt];
      }
      snorm[tid] = norm;
      slab[tid] = lbl;
    }
    __syncthreads();
    if (t >= 0) {
      int nanch = NA - a0; if (nanch > 256) nanch = 256;
      int nf4 = nanch * (NCg / 4);
      float4* o = (float4*)(out_ts + ((size_t)b * NA + a0) * NCg);
      for (int i = tid; i < nf4; i += 256) {
        int aa = i / (NCg / 4);
        int c0 = (i % (NCg / 4)) * 4;
        int lb = slab[aa];
        float nv = snorm[aa];
        float4 w = make_float4(0.0f, 0.0f, 0.0f, 0.0f);
        int d = lb - c0;
        if (d >= 0 && d < 4) ((float*)&w)[d] = nv;
        o[i] = w;
      }
    }
  }
}

extern "C" void kernel_launch(void* const* d_in, const int* in_sizes, int n_in,
                              void* d_out, int out_size, void* d_ws, size_t ws_size,
                              hipStream_t stream) {
  const float* pd_scores = (const float*)d_in[0];
  const float* pd_bboxes = (const float*)d_in[1];
  const float* anc       = (const float*)d_in[2];
  const float* gt_labels = (const float*)d_in[3];
  const float* gt_bboxes = (const float*)d_in[4];
  const int*   mask_gt   = (const int*)d_in[5];

  int NA = in_sizes[2] / 2;       // 8400
  int B  = in_sizes[3] / NBg;     // 16
  size_t nBA = (size_t)B * NA;

  float* out_tb = (float*)d_out;              // (B,NA,4)
  float* out_ts = out_tb + nBA * 4;           // (B,NA,80)
  float* out_fg = out_ts + nBA * NCg;         // (B,NA)

  char* ws = (char*)d_ws;
  size_t off = 0;
  unsigned* bar = (unsigned*)(ws + off);      off += 256;   // cnt, gen (padded)
  int* sel = (int*)(ws + off);                off += (size_t)B * NBg * KTOP * 4;
  float* posAlign = (float*)(ws + off);       off += (size_t)B * NBg * 4;
  float* posOv = (float*)(ws + off);          off += (size_t)B * NBg * 4;

  hipMemsetAsync(bar, 0, 8, stream);

  int nTiles = (NA + 255) / 256;              // 33
  int totalTiles = B * nTiles;                // 528
  int grid = (B * NBg) / 2;                   // 512 (co-resident: 2 blocks/CU)
  fused_all<<<grid, 256, 0, stream>>>(pd_scores, pd_bboxes, anc, gt_labels,
                                      gt_bboxes, mask_gt, sel, posAlign, posOv,
                                      bar, out_tb, out_ts, out_fg,
                                      NA, nTiles, totalTiles);
}

// Round 10
// 321.407 us; speedup vs baseline: 1.0086x; 1.0086x over previous
//
#include <hip/hip_runtime.h>
#include <cstdint>
#include <cstddef>

#define NBg 64    // num gt slots
#define NCg 80    // num classes
#define KTOP 10
#define K16 16    // padded list size for bitonic merging
#define MAXSEL (NBg * KTOP)   // 640

typedef unsigned long long u64k;

// CIoU exactly mirroring the reference op order, f32, no FMA contraction.
__device__ __forceinline__ float ciou_dev(float gx1, float gy1, float gx2, float gy2,
                                          float px1, float py1, float px2, float py2) {
#pragma clang fp contract(off)
  const float keps = 1e-7f;
  float w1 = gx2 - gx1;
  float h1 = (gy2 - gy1) + keps;
  float w2 = px2 - px1;
  float h2 = (py2 - py1) + keps;
  float iw = fminf(gx2, px2) - fmaxf(gx1, px1);
  float ih = fminf(gy2, py2) - fmaxf(gy1, py1);
  float inter = fmaxf(iw, 0.0f) * fmaxf(ih, 0.0f);
  float uni = w1 * h1 + w2 * h2 - inter + keps;
  float iou = inter / uni;
  float cw = fmaxf(gx2, px2) - fminf(gx1, px1);
  float ch = fmaxf(gy2, py2) - fminf(gy1, py1);
  float c2 = cw * cw + ch * ch + keps;
  float dx = (gx1 + gx2) * 0.5f - (px1 + px2) * 0.5f;
  float dy = (gy1 + gy2) * 0.5f - (py1 + py2) * 0.5f;
  float rho2 = dx * dx + dy * dy;
  float q2 = w2 / h2;
  float q1 = w1 / h1;
  float t = (float)atan((double)q2) - (float)atan((double)q1);
  float v = 0.4052847345693511f * (t * t);
  float alpha = v / ((v - iou) + 1.0000001f);
  return iou - (rho2 / c2 + v * alpha);
}

// am = sqrt(score) * overlap^6 with the exact double-rounded forms used since r1.
__device__ __forceinline__ float am_dev(float sc, float ov) {
  float f1 = (float)sqrt((double)sc);
  double o = (double)ov;
  double o3 = o * o * o;
  return f1 * (float)(o3 * o3);
}

// key = (float_bits(am) << 32) | ~idx : total order == (am desc, idx asc).
__device__ __forceinline__ u64k mk_key(float am, int a) {
  return ((u64k)__float_as_uint(am) << 32) | (unsigned)(~a);
}

// Merge two sorted-desc 16-lists (unique keys), keep top-16 sorted desc in L.
__device__ __forceinline__ void merge16(u64k (&L)[K16], const u64k (&B)[K16]) {
  u64k C[K16];
#pragma unroll
  for (int i = 0; i < K16; i++) {
    u64k x = L[i], y = B[15 - i];
    C[i] = x > y ? x : y;
  }
#pragma unroll
  for (int s = 8; s > 0; s >>= 1) {
#pragma unroll
    for (int i = 0; i < K16; i++) {
      if ((i & s) == 0) {
        u64k x = C[i], y = C[i | s];
        C[i] = x > y ? x : y;
        C[i | s] = x > y ? y : x;
      }
    }
  }
#pragma unroll
  for (int i = 0; i < K16; i++) L[i] = C[i];
}

// KAC: per gt row (1024 blocks): rect-enumerated exact top-10 -> sel[row][10];
//      plus each block fills its slice of the default outputs
//      (fg=0, tb=gt_bboxes[b][0], ts=0). KB later overwrites selected anchors.
__global__ void kac_topk_fill(const float* __restrict__ pd_scores,
                              const float* __restrict__ pd_bboxes,
                              const float* __restrict__ anc,
                              const float* __restrict__ gt_labels,
                              const float* __restrict__ gt_bboxes,
                              const int* __restrict__ mask_gt,
                              int* __restrict__ sel,
                              float* __restrict__ out_tb,
                              float* __restrict__ out_ts,
                              float* __restrict__ out_fg,
                              int NA) {
  int row = blockIdx.x;            // b*64 + j
  int tid = threadIdx.x;
  int lane = tid & 63;
  int wid = tid >> 6;
  int b = row >> 6;
  int j = row & 63;
  bool rowvalid = mask_gt[row] != 0;   // block-uniform
  const float2* anc2 = (const float2*)anc;
  __shared__ u64k xl[4][K16];

  if (rowvalid) {
    const float* g = gt_bboxes + (size_t)row * 4;
    float gx1 = g[0], gy1 = g[1], gx2 = g[2], gy2 = g[3];
    float gl = gt_labels[row];
    int lbl = gl > 0.0f ? (int)gl : 0;
    bool glpos = (gl >= 0.0f);

    auto rect = [&](float s, int n, int& x0, int& y0, int& w, int& h) {
      int i0 = (int)floorf(gx1 / s - 0.5f) - 1; if (i0 < 0) i0 = 0;
      int i1 = (int)ceilf (gx2 / s - 0.5f) + 1; if (i1 > n - 1) i1 = n - 1;
      int j0 = (int)floorf(gy1 / s - 0.5f) - 1; if (j0 < 0) j0 = 0;
      int j1 = (int)ceilf (gy2 / s - 0.5f) + 1; if (j1 > n - 1) j1 = n - 1;
      x0 = i0; y0 = j0;
      w = i1 - i0 + 1; h = j1 - j0 + 1;
      if (w < 0) w = 0;
      if (h < 0) h = 0;
    };
    int x00, y00, w0, h0, x01, y01, w1, h1, x02, y02, w2, h2;
    rect( 8.0f, 80, x00, y00, w0, h0);
    rect(16.0f, 40, x01, y01, w1, h1);
    rect(32.0f, 20, x02, y02, w2, h2);
    int sz0 = w0 * h0, sz1 = w1 * h1, sz2 = w2 * h2;
    int tot = sz0 + sz1 + sz2;

    u64k k[KTOP];
#pragma unroll
    for (int q = 0; q < KTOP; q++) k[q] = 0;

    auto ins = [&](u64k key) {
      if (key > k[KTOP - 1]) {
        k[KTOP - 1] = key;
#pragma unroll
        for (int q = KTOP - 1; q > 0; q--) {
          if (k[q] > k[q - 1]) { u64k t = k[q]; k[q] = k[q - 1]; k[q - 1] = t; }
        }
      }
    };

    for (int c = tid; c < tot; c += 256) {
      int cc, x0, y0, w, nbase, ngrid; float ss;
      if (c < sz0)            { cc = c;             x0 = x00; y0 = y00; w = w0; nbase = 0;    ngrid = 80; ss =  8.0f; }
      else if (c < sz0 + sz1) { cc = c - sz0;       x0 = x01; y0 = y01; w = w1; nbase = 6400; ngrid = 40; ss = 16.0f; }
      else                    { cc = c - sz0 - sz1; x0 = x02; y0 = y02; w = w2; nbase = 8000; ngrid = 20; ss = 32.0f; }
      int iy = y0 + cc / w;
      int ix = x0 + cc % w;
      float ax = ((float)ix + 0.5f) * ss;   // bit-identical to stored anc
      float ay = ((float)iy + 0.5f) * ss;
      float dmin = fminf(fminf(ax - gx1, ay - gy1), fminf(gx2 - ax, gy2 - ay));
      if (dmin > 1e-9f) {
        int a = nbase + iy * ngrid + ix;
        const float4 pb = ((const float4*)pd_bboxes)[(size_t)b * NA + a];
        float ci = ciou_dev(gx1, gy1, gx2, gy2, pb.x, pb.y, pb.z, pb.w);
        float ov = ci > 0.0f ? ci : 0.0f;
        float sc = glpos ? pd_scores[((size_t)b * NA + a) * NCg + lbl] : 0.0f;
        ins(mk_key(am_dev(sc, ov), a));
      }
    }

    u64k L[K16];
#pragma unroll
    for (int q = 0; q < KTOP; q++) L[q] = k[q];
#pragma unroll
    for (int q = KTOP; q < K16; q++) L[q] = 0;

#pragma unroll
    for (int step = 0; step < 6; step++) {
      u64k B[K16];
#pragma unroll
      for (int q = 0; q < K16; q++)
        B[q] = __shfl_xor((unsigned long long)L[q], 1 << step, 64);
      merge16(L, B);
    }
    if (lane < K16) xl[wid][lane] = L[lane];
    __syncthreads();
    if (wid == 2) {                  // 2 <- merge(2,3)
      u64k B[K16];
#pragma unroll
      for (int q = 0; q < K16; q++) B[q] = xl[3][q];
      merge16(L, B);
      if (lane < K16) xl[2][lane] = L[lane];
    }
    if (wid == 0) {                  // 0 <- merge(0,1)
      u64k B[K16];
#pragma unroll
      for (int q = 0; q < K16; q++) B[q] = xl[1][q];
      merge16(L, B);
    }
    __syncthreads();
    if (wid == 0) {
      u64k B[K16];
#pragma unroll
      for (int q = 0; q < K16; q++) B[q] = xl[2][q];
      merge16(L, B);                 // global top-16, sorted desc
      if (lane == 0) {
        int npos = 0;
#pragma unroll
        for (int q = 0; q < KTOP; q++) if ((L[q] >> 32) != 0) npos++;
        int cand = 0;
        for (int slot = 0; slot < KTOP; slot++) {
          int a;
          if (slot < npos) {
            a = (int)~(unsigned)L[slot];
          } else {
            bool moved = true;
            while (moved) {
              moved = false;
#pragma unroll
              for (int q = 0; q < KTOP; q++)
                if (q < npos && (int)~(unsigned)L[q] == cand) { cand++; moved = true; }
            }
            a = cand++;
          }
          float2 ap = anc2[a];
          float dmin = fminf(fminf(ap.x - gx1, ap.y - gy1),
                             fminf(gx2 - ap.x, gy2 - ap.y));
          sel[row * KTOP + slot] = (dmin > 1e-9f) ? a : -1;
        }
      }
    }
  } else {
    if (tid < KTOP) sel[row * KTOP + tid] = -1;
  }

  // ---- default-output fill: this block covers anchors [start,end) of batch b
  int start = (j * NA) >> 6;
  int end = ((j + 1) * NA) >> 6;
  float4 g0 = ((const float4*)gt_bboxes)[(size_t)b * NBg];  // gt 0 of batch b
  float4* tb4 = (float4*)out_tb;
  for (int a = start + tid; a < end; a += 256) {
    tb4[(size_t)b * NA + a] = g0;
    out_fg[(size_t)b * NA + a] = 0.0f;
  }
  float4 z = make_float4(0.0f, 0.0f, 0.0f, 0.0f);
  float4* ts4 = (float4*)out_ts + (size_t)b * NA * (NCg / 4);
  int i0 = start * (NCg / 4), i1 = end * (NCg / 4);
  for (int i = i0 + tid; i < i1; i += 256) ts4[i] = z;
}

// KB: one block per batch. Scatter sel -> per-anchor 64-bit masks in LDS,
// resolve only marked anchors (bit-identical arithmetic), per-gt pos maxes
// via LDS atomics, then scatter-write fg/tb and the single ts[label] float.
__global__ void kb_resolve(const float* __restrict__ pd_scores,
                           const float* __restrict__ pd_bboxes,
                           const float* __restrict__ anc,
                           const float* __restrict__ gt_labels,
                           const float* __restrict__ gt_bboxes,
                           const int* __restrict__ mask_gt,
                           const int* __restrict__ sel,
                           float* __restrict__ out_tb,
                           float* __restrict__ out_ts,
                           float* __restrict__ out_fg,
                           int NA) {
  int b = blockIdx.x;
  int tid = threadIdx.x;
  __shared__ unsigned mlo[8400], mhi[8400];
  __shared__ float4 sg[NBg];
  __shared__ int svalid[NBg], slbl[NBg], sglpos[NBg];
  __shared__ int spaI[NBg], spoI[NBg];
  __shared__ int ca[MAXSEL], ct[MAXSEL];
  __shared__ float cam[MAXSEL];
  __shared__ int scc;

  for (int i = tid; i < 8400; i += 256) { mlo[i] = 0u; mhi[i] = 0u; }
  if (tid < NBg) {
    int j = tid;
    const float* gg = gt_bboxes + ((size_t)b * NBg + j) * 4;
    sg[j] = make_float4(gg[0], gg[1], gg[2], gg[3]);
    svalid[j] = mask_gt[b * NBg + j];
    float gl = gt_labels[b * NBg + j];
    slbl[j] = gl > 0.0f ? (int)gl : 0;
    sglpos[j] = (gl >= 0.0f) ? 1 : 0;
    spaI[j] = 0; spoI[j] = 0;
  }
  if (tid == 0) scc = 0;
  __syncthreads();

  for (int i = tid; i < MAXSEL; i += 256) {
    int e = sel[b * MAXSEL + i];
    if (e >= 0) {
      int j = i / KTOP;
      if (j < 32) atomicOr(&mlo[e], 1u << j);
      else        atomicOr(&mhi[e], 1u << (j - 32));
    }
  }
  __syncthreads();

  const float2* anc2 = (const float2*)anc;
  for (int a = tid; a < NA; a += 256) {
    unsigned lo = mlo[a], hi = mhi[a];
    if (!(lo | hi)) continue;
    int cnt = __popc(lo) + __popc(hi);
    int first = lo ? (__ffs(lo) - 1) : (32 + __ffs(hi) - 1);
    const float* pb = pd_bboxes + ((size_t)b * NA + a) * 4;
    float px1 = pb[0], py1 = pb[1], px2 = pb[2], py2 = pb[3];
    float2 ap = anc2[a];
    float ax = ap.x, ay = ap.y;

    int t;
    float ovt = -1.0f;
    if (cnt == 1) {
      t = first;
    } else {
      // cheap in-box&valid bitmask over all 64 gts, then CIoU on set bits
      unsigned bm_lo = 0u, bm_hi = 0u;
      for (int jj = 0; jj < NBg; jj++) {
        if (svalid[jj]) {
          float4 gq = sg[jj];
          float dmin = fminf(fminf(ax - gq.x, ay - gq.y), fminf(gq.z - ax, gq.w - ay));
          if (dmin > 1e-9f) {
            if (jj < 32) bm_lo |= 1u << jj; else bm_hi |= 1u << (jj - 32);
          }
        }
      }
      float best = 0.0f;
      t = 0;
      unsigned m = bm_lo; int base = 0;
      for (int hh = 0; hh < 2; hh++) {
        while (m) {
          int jj = base + __ffs(m) - 1; m &= m - 1;
          float4 gq = sg[jj];
          float ci = ciou_dev(gq.x, gq.y, gq.z, gq.w, px1, py1, px2, py2);
          float ov = ci > 0.0f ? ci : 0.0f;
          if (ov > best) { best = ov; t = jj; }
        }
        m = bm_hi; base = 32;
      }
      ovt = best;
    }
    float ov;
    float4 gb = sg[t];
    if (ovt >= 0.0f) {
      ov = ovt;
    } else {
      float ci = ciou_dev(gb.x, gb.y, gb.z, gb.w, px1, py1, px2, py2);
      ov = ci > 0.0f ? ci : 0.0f;
    }
    float sc = sglpos[t] ? pd_scores[((size_t)b * NA + a) * NCg + slbl[t]] : 0.0f;
    float amval = am_dev(sc, ov);
    atomicMax(&spaI[t], __float_as_int(amval));
    atomicMax(&spoI[t], __float_as_int(ov));
    int p = atomicAdd(&scc, 1);
    ca[p] = a; ct[p] = t; cam[p] = amval;
  }
  __syncthreads();

  int n = scc;
  for (int i = tid; i < n; i += 256) {
    int a = ca[i], t = ct[i];
    float norm = cam[i] * __int_as_float(spoI[t]) / (__int_as_float(spaI[t]) + 1e-9f);
    out_fg[(size_t)b * NA + a] = 1.0f;
    ((float4*)out_tb)[(size_t)b * NA + a] = sg[t];
    out_ts[((size_t)b * NA + a) * NCg + slbl[t]] = norm;
  }
}

extern "C" void kernel_launch(void* const* d_in, const int* in_sizes, int n_in,
                              void* d_out, int out_size, void* d_ws, size_t ws_size,
                              hipStream_t stream) {
  const float* pd_scores = (const float*)d_in[0];
  const float* pd_bboxes = (const float*)d_in[1];
  const float* anc       = (const float*)d_in[2];
  const float* gt_labels = (const float*)d_in[3];
  const float* gt_bboxes = (const float*)d_in[4];
  const int*   mask_gt   = (const int*)d_in[5];

  int NA = in_sizes[2] / 2;       // 8400
  int B  = in_sizes[3] / NBg;     // 16
  size_t nBA = (size_t)B * NA;

  float* out_tb = (float*)d_out;              // (B,NA,4)
  float* out_ts = out_tb + nBA * 4;           // (B,NA,80)
  float* out_fg = out_ts + nBA * NCg;         // (B,NA)

  int* sel = (int*)d_ws;                      // B*64*10 ints

  dim3 blk(256);
  kac_topk_fill<<<B * NBg, blk, 0, stream>>>(pd_scores, pd_bboxes, anc, gt_labels,
                                             gt_bboxes, mask_gt, sel,
                                             out_tb, out_ts, out_fg, NA);
  kb_resolve<<<B, blk, 0, stream>>>(pd_scores, pd_bboxes, anc, gt_labels,
                                    gt_bboxes, mask_gt, sel,
                                    out_tb, out_ts, out_fg, NA);
}

// Round 11
// 147.788 us; speedup vs baseline: 2.1935x; 2.1748x over previous
//
#include <hip/hip_runtime.h>
#include <cstdint>
#include <cstddef>

#define NBg 64    // num gt slots
#define NCg 80    // num classes
#define KTOP 10
#define K16 16    // padded list size for bitonic merging
#define MAXSEL (NBg * KTOP)   // 640
#define ENTCAP 768            // per-batch entry capacity (>= 640)

typedef unsigned long long u64k;

// CIoU exactly mirroring the reference op order, f32, no FMA contraction.
__device__ __forceinline__ float ciou_dev(float gx1, float gy1, float gx2, float gy2,
                                          float px1, float py1, float px2, float py2) {
#pragma clang fp contract(off)
  const float keps = 1e-7f;
  float w1 = gx2 - gx1;
  float h1 = (gy2 - gy1) + keps;
  float w2 = px2 - px1;
  float h2 = (py2 - py1) + keps;
  float iw = fminf(gx2, px2) - fmaxf(gx1, px1);
  float ih = fminf(gy2, py2) - fmaxf(gy1, py1);
  float inter = fmaxf(iw, 0.0f) * fmaxf(ih, 0.0f);
  float uni = w1 * h1 + w2 * h2 - inter + keps;
  float iou = inter / uni;
  float cw = fmaxf(gx2, px2) - fminf(gx1, px1);
  float ch = fmaxf(gy2, py2) - fminf(gy1, py1);
  float c2 = cw * cw + ch * ch + keps;
  float dx = (gx1 + gx2) * 0.5f - (px1 + px2) * 0.5f;
  float dy = (gy1 + gy2) * 0.5f - (py1 + py2) * 0.5f;
  float rho2 = dx * dx + dy * dy;
  float q2 = w2 / h2;
  float q1 = w1 / h1;
  float t = (float)atan((double)q2) - (float)atan((double)q1);
  float v = 0.4052847345693511f * (t * t);
  float alpha = v / ((v - iou) + 1.0000001f);
  return iou - (rho2 / c2 + v * alpha);
}

// am = sqrt(score) * overlap^6 with the exact double-rounded forms used since r1.
__device__ __forceinline__ float am_dev(float sc, float ov) {
  float f1 = (float)sqrt((double)sc);
  double o = (double)ov;
  double o3 = o * o * o;
  return f1 * (float)(o3 * o3);
}

// key = (float_bits(am) << 32) | ~idx : total order == (am desc, idx asc).
__device__ __forceinline__ u64k mk_key(float am, int a) {
  return ((u64k)__float_as_uint(am) << 32) | (unsigned)(~a);
}

// Merge two sorted-desc 16-lists (unique keys), keep top-16 sorted desc in L.
__device__ __forceinline__ void merge16(u64k (&L)[K16], const u64k (&B)[K16]) {
  u64k C[K16];
#pragma unroll
  for (int i = 0; i < K16; i++) {
    u64k x = L[i], y = B[15 - i];
    C[i] = x > y ? x : y;
  }
#pragma unroll
  for (int s = 8; s > 0; s >>= 1) {
#pragma unroll
    for (int i = 0; i < K16; i++) {
      if ((i & s) == 0) {
        u64k x = C[i], y = C[i | s];
        C[i] = x > y ? x : y;
        C[i | s] = x > y ? y : x;
      }
    }
  }
#pragma unroll
  for (int i = 0; i < K16; i++) L[i] = C[i];
}

// KAC: per gt row (1024 blocks): rect-enumerated exact top-10 -> sel[row][10];
// also zero-inits posAlign/posOv/entcnt, and fills default outputs
// (fg=0, tb=gt_bboxes[b][0], ts=0). Later kernels overwrite marked anchors.
__global__ void kac_topk_fill(const float* __restrict__ pd_scores,
                              const float* __restrict__ pd_bboxes,
                              const float* __restrict__ anc,
                              const float* __restrict__ gt_labels,
                              const float* __restrict__ gt_bboxes,
                              const int* __restrict__ mask_gt,
                              int* __restrict__ sel,
                              float* __restrict__ posAlign,
                              float* __restrict__ posOv,
                              int* __restrict__ entcnt,
                              float* __restrict__ out_tb,
                              float* __restrict__ out_ts,
                              float* __restrict__ out_fg,
                              int NA) {
  int row = blockIdx.x;            // b*64 + j
  int tid = threadIdx.x;
  int lane = tid & 63;
  int wid = tid >> 6;
  int b = row >> 6;
  int j = row & 63;
  if (tid == 0) { posAlign[row] = 0.0f; posOv[row] = 0.0f; }
  if (tid == 1 && j == 0) entcnt[b] = 0;
  bool rowvalid = mask_gt[row] != 0;   // block-uniform
  const float2* anc2 = (const float2*)anc;
  __shared__ u64k xl[4][K16];

  if (rowvalid) {
    const float* g = gt_bboxes + (size_t)row * 4;
    float gx1 = g[0], gy1 = g[1], gx2 = g[2], gy2 = g[3];
    float gl = gt_labels[row];
    int lbl = gl > 0.0f ? (int)gl : 0;
    bool glpos = (gl >= 0.0f);

    auto rect = [&](float s, int n, int& x0, int& y0, int& w, int& h) {
      int i0 = (int)floorf(gx1 / s - 0.5f) - 1; if (i0 < 0) i0 = 0;
      int i1 = (int)ceilf (gx2 / s - 0.5f) + 1; if (i1 > n - 1) i1 = n - 1;
      int j0 = (int)floorf(gy1 / s - 0.5f) - 1; if (j0 < 0) j0 = 0;
      int j1 = (int)ceilf (gy2 / s - 0.5f) + 1; if (j1 > n - 1) j1 = n - 1;
      x0 = i0; y0 = j0;
      w = i1 - i0 + 1; h = j1 - j0 + 1;
      if (w < 0) w = 0;
      if (h < 0) h = 0;
    };
    int x00, y00, w0, h0, x01, y01, w1, h1, x02, y02, w2, h2;
    rect( 8.0f, 80, x00, y00, w0, h0);
    rect(16.0f, 40, x01, y01, w1, h1);
    rect(32.0f, 20, x02, y02, w2, h2);
    int sz0 = w0 * h0, sz1 = w1 * h1, sz2 = w2 * h2;
    int tot = sz0 + sz1 + sz2;

    u64k k[KTOP];
#pragma unroll
    for (int q = 0; q < KTOP; q++) k[q] = 0;

    auto ins = [&](u64k key) {
      if (key > k[KTOP - 1]) {
        k[KTOP - 1] = key;
#pragma unroll
        for (int q = KTOP - 1; q > 0; q--) {
          if (k[q] > k[q - 1]) { u64k t = k[q]; k[q] = k[q - 1]; k[q - 1] = t; }
        }
      }
    };

    for (int c = tid; c < tot; c += 256) {
      int cc, x0, y0, w, nbase, ngrid; float ss;
      if (c < sz0)            { cc = c;             x0 = x00; y0 = y00; w = w0; nbase = 0;    ngrid = 80; ss =  8.0f; }
      else if (c < sz0 + sz1) { cc = c - sz0;       x0 = x01; y0 = y01; w = w1; nbase = 6400; ngrid = 40; ss = 16.0f; }
      else                    { cc = c - sz0 - sz1; x0 = x02; y0 = y02; w = w2; nbase = 8000; ngrid = 20; ss = 32.0f; }
      int iy = y0 + cc / w;
      int ix = x0 + cc % w;
      float ax = ((float)ix + 0.5f) * ss;   // bit-identical to stored anc
      float ay = ((float)iy + 0.5f) * ss;
      float dmin = fminf(fminf(ax - gx1, ay - gy1), fminf(gx2 - ax, gy2 - ay));
      if (dmin > 1e-9f) {
        int a = nbase + iy * ngrid + ix;
        const float4 pb = ((const float4*)pd_bboxes)[(size_t)b * NA + a];
        float ci = ciou_dev(gx1, gy1, gx2, gy2, pb.x, pb.y, pb.z, pb.w);
        float ov = ci > 0.0f ? ci : 0.0f;
        float sc = glpos ? pd_scores[((size_t)b * NA + a) * NCg + lbl] : 0.0f;
        ins(mk_key(am_dev(sc, ov), a));
      }
    }

    u64k L[K16];
#pragma unroll
    for (int q = 0; q < KTOP; q++) L[q] = k[q];
#pragma unroll
    for (int q = KTOP; q < K16; q++) L[q] = 0;

#pragma unroll
    for (int step = 0; step < 6; step++) {
      u64k B[K16];
#pragma unroll
      for (int q = 0; q < K16; q++)
        B[q] = __shfl_xor((unsigned long long)L[q], 1 << step, 64);
      merge16(L, B);
    }
    if (lane < K16) xl[wid][lane] = L[lane];
    __syncthreads();
    if (wid == 2) {                  // 2 <- merge(2,3)
      u64k B[K16];
#pragma unroll
      for (int q = 0; q < K16; q++) B[q] = xl[3][q];
      merge16(L, B);
      if (lane < K16) xl[2][lane] = L[lane];
    }
    if (wid == 0) {                  // 0 <- merge(0,1)
      u64k B[K16];
#pragma unroll
      for (int q = 0; q < K16; q++) B[q] = xl[1][q];
      merge16(L, B);
    }
    __syncthreads();
    if (wid == 0) {
      u64k B[K16];
#pragma unroll
      for (int q = 0; q < K16; q++) B[q] = xl[2][q];
      merge16(L, B);                 // global top-16, sorted desc
      if (lane == 0) {
        int npos = 0;
#pragma unroll
        for (int q = 0; q < KTOP; q++) if ((L[q] >> 32) != 0) npos++;
        int cand = 0;
        for (int slot = 0; slot < KTOP; slot++) {
          int a;
          if (slot < npos) {
            a = (int)~(unsigned)L[slot];
          } else {
            bool moved = true;
            while (moved) {
              moved = false;
#pragma unroll
              for (int q = 0; q < KTOP; q++)
                if (q < npos && (int)~(unsigned)L[q] == cand) { cand++; moved = true; }
            }
            a = cand++;
          }
          float2 ap = anc2[a];
          float dmin = fminf(fminf(ap.x - gx1, ap.y - gy1),
                             fminf(gx2 - ap.x, gy2 - ap.y));
          sel[row * KTOP + slot] = (dmin > 1e-9f) ? a : -1;
        }
      }
    }
  } else {
    if (tid < KTOP) sel[row * KTOP + tid] = -1;
  }

  // ---- default-output fill: this block covers anchors [start,end) of batch b
  int start = (j * NA) >> 6;
  int end = ((j + 1) * NA) >> 6;
  float4 g0 = ((const float4*)gt_bboxes)[(size_t)b * NBg];  // gt 0 of batch b
  float4* tb4 = (float4*)out_tb;
  for (int a = start + tid; a < end; a += 256) {
    tb4[(size_t)b * NA + a] = g0;
    out_fg[(size_t)b * NA + a] = 0.0f;
  }
  float4 z = make_float4(0.0f, 0.0f, 0.0f, 0.0f);
  float4* ts4 = (float4*)out_ts + (size_t)b * NA * (NCg / 4);
  int i0 = start * (NCg / 4), i1 = end * (NCg / 4);
  for (int i = i0 + tid; i < i1; i += 256) ts4[i] = z;
}

// K3 sparse: 528 tile-blocks (16 batches x 33 tiles of 256 anchors).
// LDS scatter sel -> per-anchor 64-bit mask; resolve ONLY marked anchors
// (bit-identical arithmetic); write fg=1/tb; global atomicMax posAlign/posOv;
// append {a,t,amval} to per-batch compact entry list.
__global__ void k3_sparse(const float* __restrict__ pd_scores,
                          const float* __restrict__ pd_bboxes,
                          const float* __restrict__ anc,
                          const float* __restrict__ gt_labels,
                          const float* __restrict__ gt_bboxes,
                          const int* __restrict__ mask_gt,
                          const int* __restrict__ sel,
                          float* __restrict__ posAlign,
                          float* __restrict__ posOv,
                          int* __restrict__ entcnt,
                          int* __restrict__ ent_a,
                          int* __restrict__ ent_t,
                          float* __restrict__ ent_am,
                          float* __restrict__ out_tb,
                          float* __restrict__ out_fg,
                          int NA) {
  int b = blockIdx.y;
  int tid = threadIdx.x;
  int a0 = blockIdx.x * 256;
  int a = a0 + tid;
  __shared__ float4 sg[NBg];
  __shared__ int svalid[NBg], slbl[NBg], sglpos[NBg];
  __shared__ unsigned mlo[256], mhi[256];
  mlo[tid] = 0u; mhi[tid] = 0u;
  if (tid < NBg) {
    int j = tid;
    const float* gg = gt_bboxes + ((size_t)b * NBg + j) * 4;
    sg[j] = make_float4(gg[0], gg[1], gg[2], gg[3]);
    svalid[j] = mask_gt[b * NBg + j];
    float gl = gt_labels[b * NBg + j];
    slbl[j] = gl > 0.0f ? (int)gl : 0;
    sglpos[j] = (gl >= 0.0f) ? 1 : 0;
  }
  __syncthreads();
  for (int i = tid; i < MAXSEL; i += 256) {
    int e = sel[b * MAXSEL + i];
    int d = e - a0;
    if (d >= 0 && d < 256) {
      int j = i / KTOP;
      unsigned bit = 1u << (j & 31);
      if (j < 32) atomicOr(&mlo[d], bit); else atomicOr(&mhi[d], bit);
    }
  }
  __syncthreads();
  if (a >= NA) return;
  unsigned lo = mlo[tid], hi = mhi[tid];
  if (!(lo | hi)) return;           // defaults already written by kac
  int cnt = __popc(lo) + __popc(hi);
  int first = lo ? (__ffs(lo) - 1) : (32 + __ffs(hi) - 1);

  const float* pb = pd_bboxes + ((size_t)b * NA + a) * 4;
  float px1 = pb[0], py1 = pb[1], px2 = pb[2], py2 = pb[3];
  float ax = anc[2 * a], ay = anc[2 * a + 1];

  int t;
  float ovt = -1.0f;
  if (cnt == 1) {
    t = first;
  } else {
    // cheap in-box&valid bitmask over 64 gts, then CIoU only on set bits
    unsigned bm_lo = 0u, bm_hi = 0u;
    for (int jj = 0; jj < NBg; jj++) {
      if (svalid[jj]) {
        float4 gq = sg[jj];
        float dmin = fminf(fminf(ax - gq.x, ay - gq.y), fminf(gq.z - ax, gq.w - ay));
        if (dmin > 1e-9f) {
          if (jj < 32) bm_lo |= 1u << jj; else bm_hi |= 1u << (jj - 32);
        }
      }
    }
    float best = 0.0f;
    t = 0;
    unsigned m = bm_lo; int base = 0;
    for (int hh = 0; hh < 2; hh++) {
      while (m) {
        int jj = base + __ffs(m) - 1; m &= m - 1;
        float4 gq = sg[jj];
        float ci = ciou_dev(gq.x, gq.y, gq.z, gq.w, px1, py1, px2, py2);
        float ov = ci > 0.0f ? ci : 0.0f;
        if (ov > best) { best = ov; t = jj; }
      }
      m = bm_hi; base = 32;
    }
    ovt = best;
  }
  float4 gb = sg[t];
  float ov;
  if (ovt >= 0.0f) {
    ov = ovt;
  } else {
    float ci = ciou_dev(gb.x, gb.y, gb.z, gb.w, px1, py1, px2, py2);
    ov = ci > 0.0f ? ci : 0.0f;     // t came from sel -> in-box & valid
  }
  float sc = sglpos[t] ? pd_scores[((size_t)b * NA + a) * NCg + slbl[t]] : 0.0f;
  float amval = am_dev(sc, ov);
  atomicMax((int*)(posAlign + b * NBg + t), __float_as_int(amval));
  atomicMax((int*)(posOv + b * NBg + t), __float_as_int(ov));
  out_fg[(size_t)b * NA + a] = 1.0f;
  ((float4*)out_tb)[(size_t)b * NA + a] = gb;
  int p = atomicAdd(&entcnt[b], 1);
  if (p < ENTCAP) { ent_a[b * ENTCAP + p] = a; ent_t[b * ENTCAP + p] = t; ent_am[b * ENTCAP + p] = amval; }
}

// K5 sparse: 64 blocks (4 per batch). For each entry: norm + single ts float.
// Pure independent global ops -> safe at low block count.
__global__ void k5_sparse(const float* __restrict__ gt_labels,
                          const float* __restrict__ posAlign,
                          const float* __restrict__ posOv,
                          const int* __restrict__ entcnt,
                          const int* __restrict__ ent_a,
                          const int* __restrict__ ent_t,
                          const float* __restrict__ ent_am,
                          float* __restrict__ out_ts,
                          int NA) {
  int b = blockIdx.x >> 2;
  int sub = blockIdx.x & 3;
  int tid = threadIdx.x;
  int n = entcnt[b];
  if (n > ENTCAP) n = ENTCAP;
  for (int i = sub * 256 + tid; i < n; i += 1024) {
    int a = ent_a[b * ENTCAP + i];
    int t = ent_t[b * ENTCAP + i];
    float amval = ent_am[b * ENTCAP + i];
    float pa = posAlign[b * NBg + t];
    float po = posOv[b * NBg + t];
    float norm = amval * po / (pa + 1e-9f);
    float gl = gt_labels[b * NBg + t];
    int lbl = gl > 0.0f ? (int)gl : 0;
    out_ts[((size_t)b * NA + a) * NCg + lbl] = norm;
  }
}

extern "C" void kernel_launch(void* const* d_in, const int* in_sizes, int n_in,
                              void* d_out, int out_size, void* d_ws, size_t ws_size,
                              hipStream_t stream) {
  const float* pd_scores = (const float*)d_in[0];
  const float* pd_bboxes = (const float*)d_in[1];
  const float* anc       = (const float*)d_in[2];
  const float* gt_labels = (const float*)d_in[3];
  const float* gt_bboxes = (const float*)d_in[4];
  const int*   mask_gt   = (const int*)d_in[5];

  int NA = in_sizes[2] / 2;       // 8400
  int B  = in_sizes[3] / NBg;     // 16
  size_t nBA = (size_t)B * NA;

  float* out_tb = (float*)d_out;              // (B,NA,4)
  float* out_ts = out_tb + nBA * 4;           // (B,NA,80)
  float* out_fg = out_ts + nBA * NCg;         // (B,NA)

  char* ws = (char*)d_ws;
  size_t off = 0;
  int* sel = (int*)(ws + off);                off += (size_t)B * NBg * KTOP * 4;
  float* posAlign = (float*)(ws + off);       off += (size_t)B * NBg * 4;
  float* posOv = (float*)(ws + off);          off += (size_t)B * NBg * 4;
  int* entcnt = (int*)(ws + off);             off += 64 * 4;
  int* ent_a = (int*)(ws + off);              off += (size_t)B * ENTCAP * 4;
  int* ent_t = (int*)(ws + off);              off += (size_t)B * ENTCAP * 4;
  float* ent_am = (float*)(ws + off);         off += (size_t)B * ENTCAP * 4;

  dim3 blk(256);
  kac_topk_fill<<<B * NBg, blk, 0, stream>>>(pd_scores, pd_bboxes, anc, gt_labels,
                                             gt_bboxes, mask_gt, sel,
                                             posAlign, posOv, entcnt,
                                             out_tb, out_ts, out_fg, NA);
  dim3 g3((NA + 255) / 256, B);
  k3_sparse<<<g3, blk, 0, stream>>>(pd_scores, pd_bboxes, anc, gt_labels,
                                    gt_bboxes, mask_gt, sel,
                                    posAlign, posOv, entcnt, ent_a, ent_t, ent_am,
                                    out_tb, out_fg, NA);
  k5_sparse<<<B * 4, blk, 0, stream>>>(gt_labels, posAlign, posOv,
                                       entcnt, ent_a, ent_t, ent_am, out_ts, NA);
}